// Round 5
// baseline (286.684 us; speedup 1.0000x reference)
//
#include <hip/hip_runtime.h>
#include <stdint.h>

// Dtype model: inputs fp32, output fp32, internals bf16 MFMA.
// gamma == 0 in this instance => out = h1 + h2 = x1@Wp1 + x2@Wp2 + b1 + b2.
// R10: fused GEMM A-staging was fully UNCOALESCED (lane pairs 3KB apart ->
// 64 lines per load instr -> TA serialization; all pipes <15%). Rewritten
// coalesced: chunk=i*256+tid, row=cc>>4, c4=cc&15 -> 1KB contiguous per
// wave-instr. 1-deep prefetch (barrier drains vmcnt per iter anyway).
// h-GEMM pair merged into one gated launch (z=2). Attention path unchanged.

// ---------- types ----------
typedef __bf16 bf16x8 __attribute__((ext_vector_type(8)));
typedef float f32x4 __attribute__((ext_vector_type(4)));
typedef unsigned short u16x8 __attribute__((ext_vector_type(8)));
typedef unsigned short u16x4 __attribute__((ext_vector_type(4)));
typedef unsigned short u16x2 __attribute__((ext_vector_type(2)));

typedef __attribute__((address_space(3))) unsigned int as3_u32;
typedef const __attribute__((address_space(1))) unsigned int as1_u32;

__device__ __forceinline__ float bf2f(unsigned short h) {
  union { unsigned int u; float f; } v; v.u = ((unsigned int)h) << 16; return v.f;
}
__device__ __forceinline__ unsigned short f2bf(float f) {
  union { float f; unsigned int u; } v; v.f = f;
  unsigned int u = v.u;
  return (unsigned short)((u + 0x7fffu + ((u >> 16) & 1u)) >> 16);
}
__device__ __forceinline__ bf16x8 as_bf16x8(u16x8 x) {
  union { u16x8 u; bf16x8 b; } c; c.u = x; return c.b;
}
// async global->LDS, 16B per lane; lds base must be wave-uniform
__device__ __forceinline__ void async_load16(unsigned short* lds, const unsigned short* g) {
  __builtin_amdgcn_global_load_lds((as1_u32*)g, (as3_u32*)lds, 16, 0, 0);
}

// ---------- LDS-tiled weight transpose: dst_bf16[512][K] = src_f32[K][512] ----------
__global__ __launch_bounds__(256) void transpose_all_lds(
    const float* __restrict__ Wp1, const float* __restrict__ Wp2,
    const float* __restrict__ Wq, const float* __restrict__ Wk,
    const float* __restrict__ Wv,
    unsigned short* __restrict__ o1, unsigned short* __restrict__ o2,
    unsigned short* __restrict__ oq, unsigned short* __restrict__ ok,
    unsigned short* __restrict__ ov,
    const float* __restrict__ gamma)
{
  __shared__ unsigned short sT[64][72];  // [n][k], stride 144B (16B-aligned)
  const int bid = blockIdx.x;
  const int tid = threadIdx.x;

  const float* src; unsigned short* dst; int K, ktiles, base;
  if (bid < 96)       { src = Wp1; dst = o1; K = 768;  ktiles = 12; base = 0; }
  else if (bid < 224) { src = Wp2; dst = o2; K = 1024; ktiles = 16; base = 96; }
  else {
    if (gamma[0] == 0.0f) return;  // QKV weights only feed attention
    K = 512; ktiles = 8;
    if (bid < 288)      { src = Wq; dst = oq; base = 224; }
    else if (bid < 352) { src = Wk; dst = ok; base = 288; }
    else                { src = Wv; dst = ov; base = 352; }
  }
  const int local = bid - base;
  const int k0 = (local % ktiles) * 64;
  const int n0 = (local / ktiles) * 64;

  const int rr = tid >> 4, c4 = tid & 15;
#pragma unroll
  for (int i = 0; i < 4; ++i) {
    int row = i * 16 + rr;
    f32x4 v = *(const f32x4*)(src + (size_t)(k0 + row) * 512 + n0 + c4 * 4);
#pragma unroll
    for (int j = 0; j < 4; ++j)
      sT[c4 * 4 + j][row] = f2bf(v[j]);
  }
  __syncthreads();

  const int nr = tid >> 3, kq = tid & 7;
#pragma unroll
  for (int i = 0; i < 2; ++i) {
    int n = i * 32 + nr;
    *(u16x8*)(dst + (size_t)(n0 + n) * K + k0 + kq * 8) = *(const u16x8*)&sT[n][kq * 8];
  }
}

// ---------- fused gamma==0 output GEMM ----------
// out_f32[16384,512] = x1@Wp1 + x2@Wp2 + b1 + b2, K = 768+1024 = 1792.
// 128x128 tile, BK=64, dbuf LDS, XOR swizzle, XCD-group remap, COALESCED
// A staging (f32x4 per lane, 1KB contiguous per wave instruction).
__global__ __launch_bounds__(256) void fused_h12_out(
    const float* __restrict__ x1, const float* __restrict__ x2,
    const unsigned short* __restrict__ WT1, const unsigned short* __restrict__ WT2,
    const float* __restrict__ b1, const float* __restrict__ b2,
    float* __restrict__ out, const float* __restrict__ gamma)
{
  if (gamma[0] != 0.0f) return;  // gamma!=0 handled by the full path
  __shared__ __align__(16) unsigned short sA[2][128 * 64];
  __shared__ __align__(16) unsigned short sB[2][128 * 64];
  const int tid = threadIdx.x;
  const int lane = tid & 63;
  const int w = tid >> 6;
  const int wm = w & 1, wn = w >> 1;
  const int l15 = lane & 15, lg = lane >> 4;

  const int f = blockIdx.x;                     // 0..511
  const int bx = (f >> 3) & 3;                  // col tile (4)
  const int by = (f & 7) | ((f >> 5) << 3);     // row panel (128); same-panel
                                                // quads share f%8 -> same XCD
  const size_t row0A = (size_t)by * 128;
  const int row0B = bx * 128;

  f32x4 ar[8];                                  // A prefetch (coalesced)
  f32x4 acc[4][4] = {};

  // A tile 128x64 f32 = 2048 f32x4 chunks; thread does 8, coalesced:
  // chunk cc=i*256+tid -> row=cc>>4 (16 chunks/row), c4=cc&15.
  auto loadA = [&](int kk) {
#pragma unroll
    for (int i = 0; i < 8; ++i) {
      int cc = i * 256 + tid;
      int row = cc >> 4, c4 = cc & 15;
      const float* ap = (kk < 768)
          ? (x1 + (row0A + row) * 768 + kk + c4 * 4)
          : (x2 + (row0A + row) * 1024 + (kk - 768) + c4 * 4);
      ar[i] = *(const f32x4*)ap;
    }
  };
  // B tile = 128 rows x 64 bf16 = 1024 16B chunks -> 4 chunks/thread.
  auto stageB = [&](int kk, int buf) {
#pragma unroll
    for (int j = 0; j < 4; ++j) {
      int cc = (w * 4 + j) * 64 + lane;      // 16B chunk id 0..1023
      int r = cc >> 3, c = cc & 7;
      int cs = c ^ (r & 7);                  // pre-swizzled global source
      const unsigned short* bp = (kk < 768)
          ? (WT1 + (size_t)(row0B + r) * 768 + kk + cs * 8)
          : (WT2 + (size_t)(row0B + r) * 1024 + (kk - 768) + cs * 8);
      async_load16(&sB[buf][(size_t)(w * 4 + j) * 512], bp);
    }
  };
  // convert + swizzled ds_write_b64: logical 16B-chunk c=c4>>1, half=c4&1.
  auto writeA = [&](int buf) {
#pragma unroll
    for (int i = 0; i < 8; ++i) {
      int cc = i * 256 + tid;
      int row = cc >> 4, c4 = cc & 15;
      int c = c4 >> 1, half = c4 & 1;
      u16x4 hv;
#pragma unroll
      for (int j = 0; j < 4; ++j) hv[j] = f2bf(ar[i][j]);
      *(u16x4*)&sA[buf][row * 64 + ((c ^ (row & 7)) << 3) + (half << 2)] = hv;
    }
  };
  auto compute = [&](int buf) {
#pragma unroll
    for (int ks = 0; ks < 2; ++ks) {
      bf16x8 af[4], bfr[4];
#pragma unroll
      for (int mb = 0; mb < 4; ++mb) {
        int row = wm * 64 + mb * 16 + l15;
        int cs = (ks * 4 + lg) ^ (row & 7);
        af[mb] = *(const bf16x8*)&sA[buf][row * 64 + cs * 8];
      }
#pragma unroll
      for (int nb = 0; nb < 4; ++nb) {
        int row = wn * 64 + nb * 16 + l15;
        int cs = (ks * 4 + lg) ^ (row & 7);
        bfr[nb] = *(const bf16x8*)&sB[buf][row * 64 + cs * 8];
      }
#pragma unroll
      for (int mb = 0; mb < 4; ++mb)
#pragma unroll
        for (int nb = 0; nb < 4; ++nb)
          acc[mb][nb] = __builtin_amdgcn_mfma_f32_16x16x32_bf16(af[mb], bfr[nb], acc[mb][nb], 0, 0, 0);
    }
  };

  // prologue: stage tile 0
  loadA(0);
  stageB(0, 0);
  writeA(0);
  __syncthreads();

  const int NT = 28;  // 1792 / 64
  int cur = 0;
  for (int t = 0; t < NT; ++t) {
    if (t + 1 < NT) {            // issue next tile's loads BEFORE compute
      stageB((t + 1) * 64, cur ^ 1);
      loadA((t + 1) * 64);
    }
    compute(cur);
    if (t + 1 < NT) writeA(cur ^ 1);  // convert after MFMA hid the latency
    __syncthreads();
    cur ^= 1;
  }

  // epilogue: fp32 direct store, bias = b1 + b2
  const int colb = row0B + wn * 64;
#pragma unroll
  for (int nb = 0; nb < 4; ++nb) {
    int col = colb + nb * 16 + l15;
    float bv = b1[col] + b2[col];
#pragma unroll
    for (int mb = 0; mb < 4; ++mb) {
      size_t rowb = row0A + wm * 64 + mb * 16 + lg * 4;
#pragma unroll
      for (int r = 0; r < 4; ++r)
        out[(rowb + r) * 512 + col] = acc[mb][nb][r] + bv;
    }
  }
}

// ---------- gated h-GEMMs (gamma!=0 path): z=0 -> h1, z=1 -> h2 ----------
__global__ __launch_bounds__(256) void gemm_h12(
    const float* __restrict__ x1, const float* __restrict__ x2,
    const unsigned short* __restrict__ WT1, const unsigned short* __restrict__ WT2,
    const float* __restrict__ b1, const float* __restrict__ b2,
    unsigned short* __restrict__ h1b, unsigned short* __restrict__ h2b,
    const float* __restrict__ gate)
{
  if (gate[0] == 0.0f) return;
  const int z = blockIdx.z;
  const float* A = z ? x2 : x1;
  const unsigned short* Bt = z ? WT2 : WT1;
  const float* bias = z ? b2 : b1;
  unsigned short* C = z ? h2b : h1b;
  const int K = z ? 1024 : 768;
  const int ldc = 512;

  __shared__ __align__(16) unsigned short sA[128 * 32];
  __shared__ __align__(16) unsigned short sB[128 * 32];
  const int tid = threadIdx.x;
  const int lane = tid & 63;
  const int w = tid >> 6;
  const int wm = w & 1, wn = w >> 1;
  const int l15 = lane & 15, lg = lane >> 4;
  const size_t row0A = (size_t)blockIdx.x * 128;
  const size_t row0B = (size_t)blockIdx.y * 128;
  f32x4 acc[4][4] = {};

  for (int kb = 0; kb < K; kb += 32) {
#pragma unroll
    for (int j = 0; j < 2; ++j) {
      int cc = (w * 2 + j) * 64 + lane;
      int r = cc >> 2, k8 = cc & 3;
      async_load16(&sB[(size_t)((w * 2 + j) * 64) * 8], Bt + (row0B + r) * K + kb + k8 * 8);
    }
    {
      // coalesced A staging: 128x32 f32 tile = 1024 f32x4 chunks, 4/thread
#pragma unroll
      for (int i = 0; i < 4; ++i) {
        int cc = i * 256 + tid;
        int row = cc >> 3, c4 = cc & 7;     // 8 chunks per 32-float row
        f32x4 v = *(const f32x4*)(A + (row0A + row) * K + kb + c4 * 4);
        u16x4 hv;
#pragma unroll
        for (int j = 0; j < 4; ++j) hv[j] = f2bf(v[j]);
        *(u16x4*)&sA[row * 32 + c4 * 4] = hv;
      }
    }
    __syncthreads();
    bf16x8 af[4], bfr[4];
#pragma unroll
    for (int mb = 0; mb < 4; ++mb)
      af[mb] = *(const bf16x8*)&sA[(wm * 64 + mb * 16 + l15) * 32 + lg * 8];
#pragma unroll
    for (int nb = 0; nb < 4; ++nb)
      bfr[nb] = *(const bf16x8*)&sB[(wn * 64 + nb * 16 + l15) * 32 + lg * 8];
#pragma unroll
    for (int mb = 0; mb < 4; ++mb)
#pragma unroll
      for (int nb = 0; nb < 4; ++nb)
        acc[mb][nb] = __builtin_amdgcn_mfma_f32_16x16x32_bf16(af[mb], bfr[nb], acc[mb][nb], 0, 0, 0);
    __syncthreads();
  }

  const int colb = (int)row0B + wn * 64;
#pragma unroll
  for (int nb = 0; nb < 4; ++nb) {
    int col = colb + nb * 16 + l15;
    float bv = bias[col];
#pragma unroll
    for (int mb = 0; mb < 4; ++mb) {
      size_t rowb = row0A + wm * 64 + mb * 16 + lg * 4;
#pragma unroll
      for (int r = 0; r < 4; ++r)
        C[(rowb + r) * ldc + col] = f2bf(acc[mb][nb][r] + bv);
    }
  }
}

// ---------- QKV projections: 3 GEMMs in one launch via blockIdx.z ----------
__global__ __launch_bounds__(256) void gemm_qkv(
    const unsigned short* __restrict__ Aq,
    const unsigned short* __restrict__ Akv,
    const unsigned short* __restrict__ Wq_, const unsigned short* __restrict__ Wk_,
    const unsigned short* __restrict__ Wv_,
    const float* __restrict__ bq_, const float* __restrict__ bk_,
    const float* __restrict__ bv_,
    unsigned short* __restrict__ P,
    const float* __restrict__ gate)
{
  if (gate[0] == 0.0f) return;
  const int z = blockIdx.z;
  const unsigned short* A  = (z == 0) ? Aq : Akv;
  const unsigned short* Bt = (z == 0) ? Wq_ : (z == 1 ? Wk_ : Wv_);
  const float* bias        = (z == 0) ? bq_ : (z == 1 ? bk_ : bv_);
  unsigned short* C = P + z * 512;
  const int K = 512, ldc = 1536;

  __shared__ __align__(16) unsigned short sA[128 * 32];
  __shared__ __align__(16) unsigned short sB[128 * 32];
  const int tid = threadIdx.x;
  const int lane = tid & 63;
  const int w = tid >> 6;
  const int wm = w & 1, wn = w >> 1;
  const int l15 = lane & 15, lg = lane >> 4;
  const size_t row0A = (size_t)blockIdx.x * 128;
  const size_t row0B = (size_t)blockIdx.y * 128;
  f32x4 acc[4][4] = {};

  for (int kb = 0; kb < K; kb += 32) {
#pragma unroll
    for (int j = 0; j < 2; ++j) {
      int cc = (w * 2 + j) * 64 + lane;
      int r = cc >> 2, k8 = cc & 3;
      async_load16(&sA[(size_t)((w * 2 + j) * 64) * 8], A + (row0A + r) * K + kb + k8 * 8);
      async_load16(&sB[(size_t)((w * 2 + j) * 64) * 8], Bt + (row0B + r) * K + kb + k8 * 8);
    }
    __syncthreads();
    bf16x8 af[4], bfr[4];
#pragma unroll
    for (int mb = 0; mb < 4; ++mb)
      af[mb] = *(const bf16x8*)&sA[(wm * 64 + mb * 16 + l15) * 32 + lg * 8];
#pragma unroll
    for (int nb = 0; nb < 4; ++nb)
      bfr[nb] = *(const bf16x8*)&sB[(wn * 64 + nb * 16 + l15) * 32 + lg * 8];
#pragma unroll
    for (int mb = 0; mb < 4; ++mb)
#pragma unroll
      for (int nb = 0; nb < 4; ++nb)
        acc[mb][nb] = __builtin_amdgcn_mfma_f32_16x16x32_bf16(af[mb], bfr[nb], acc[mb][nb], 0, 0, 0);
    __syncthreads();
  }

  const int colb = (int)row0B + wn * 64;
#pragma unroll
  for (int nb = 0; nb < 4; ++nb) {
    int col = colb + nb * 16 + l15;
    float bv = bias[col];
#pragma unroll
    for (int mb = 0; mb < 4; ++mb) {
      size_t rowb = row0A + wm * 64 + mb * 16 + lg * 4;
#pragma unroll
      for (int r = 0; r < 4; ++r)
        C[(rowb + r) * ldc + col] = f2bf(acc[mb][nb][r] + bv);
    }
  }
}

// ---------- flash attention (gamma!=0 path; gamma==0 -> no-op) ----------
#define LDQ 1536
__global__ __launch_bounds__(256) void flash_attn(
    const unsigned short* __restrict__ P,
    const unsigned short* __restrict__ f1,
    const unsigned short* __restrict__ h1b,
    const unsigned short* __restrict__ h2b,
    const float* __restrict__ gamma,
    unsigned short* __restrict__ f1out,
    float* __restrict__ out32,
    int dir)
{
  const float g0 = gamma[0];
  if (g0 == 0.0f) return;  // fused_h12_out already wrote the final output

  __shared__ __align__(16) unsigned short KVs[18432];
  __shared__ __align__(16) float Sred[4608];
  __shared__ __align__(16) unsigned short Pt[1152];
  __shared__ float mstate[32], lstate[32], alpha_s[32];

  const int tid = threadIdx.x;
  const int lane = tid & 63;
  const int w = tid >> 6;
  const int l15 = lane & 15, lg = lane >> 4;
  const int wbase = w * 128;
  const int qt = blockIdx.x;
  const int b = blockIdx.y;
  const size_t qrow0 = (size_t)b * 2048 + (size_t)qt * 32;
  const size_t krow0 = (size_t)b * 2048;

  if (tid < 32) { mstate[tid] = -1e30f; lstate[tid] = 0.f; }
  __syncthreads();

  bf16x8 qf[2][4];
#pragma unroll
  for (int mb = 0; mb < 2; ++mb)
#pragma unroll
    for (int ks = 0; ks < 4; ++ks)
      qf[mb][ks] = *(const bf16x8*)(P + (qrow0 + mb * 16 + l15) * LDQ + wbase + ks * 32 + lg * 8);

  f32x4 o[2][8] = {};

  const int srow = tid >> 3, ssub = tid & 7;
  const int kvp = tid & 15, dg = tid >> 4;

  for (int kt = 0; kt < 64; ++kt) {
    const size_t kvb = krow0 + (size_t)kt * 32;
#pragma unroll
    for (int i = 0; i < 8; ++i) {
      int cc = tid + i * 256;
      int r = cc >> 6, c8 = cc & 63;
      *(u16x8*)&KVs[r * 520 + c8 * 8] = *(const u16x8*)(P + (kvb + r) * LDQ + 512 + c8 * 8);
    }
    __syncthreads();

    f32x4 sacc[2][2] = {};
#pragma unroll
    for (int ks = 0; ks < 4; ++ks)
#pragma unroll
      for (int nb = 0; nb < 2; ++nb) {
        bf16x8 kf = *(const bf16x8*)&KVs[(nb * 16 + l15) * 520 + wbase + ks * 32 + lg * 8];
#pragma unroll
        for (int mb = 0; mb < 2; ++mb)
          sacc[mb][nb] = __builtin_amdgcn_mfma_f32_16x16x32_bf16(qf[mb][ks], kf, sacc[mb][nb], 0, 0, 0);
      }
#pragma unroll
    for (int mb = 0; mb < 2; ++mb)
#pragma unroll
      for (int nb = 0; nb < 2; ++nb)
#pragma unroll
        for (int r = 0; r < 4; ++r)
          Sred[w * 1152 + (mb * 16 + lg * 4 + r) * 36 + nb * 16 + l15] = sacc[mb][nb][r];
    __syncthreads();

    {
      f32x4 sv = {};
#pragma unroll
      for (int w2 = 0; w2 < 4; ++w2)
        sv += *(const f32x4*)&Sred[w2 * 1152 + srow * 36 + ssub * 4];
      const float scale = 0.044194173824159216f;
      sv *= scale;
      float mloc = fmaxf(fmaxf(sv[0], sv[1]), fmaxf(sv[2], sv[3]));
      mloc = fmaxf(mloc, __shfl_xor(mloc, 1));
      mloc = fmaxf(mloc, __shfl_xor(mloc, 2));
      mloc = fmaxf(mloc, __shfl_xor(mloc, 4));
      float mold = mstate[srow];
      float mnew = fmaxf(mold, mloc);
      const float LOG2E = 1.4426950408889634f;
      float p0 = exp2f((sv[0] - mnew) * LOG2E);
      float p1 = exp2f((sv[1] - mnew) * LOG2E);
      float p2 = exp2f((sv[2] - mnew) * LOG2E);
      float p3 = exp2f((sv[3] - mnew) * LOG2E);
      float lloc = p0 + p1 + p2 + p3;
      lloc += __shfl_xor(lloc, 1);
      lloc += __shfl_xor(lloc, 2);
      lloc += __shfl_xor(lloc, 4);
      float alpha = exp2f((mold - mnew) * LOG2E);
      if (ssub == 0) {
        mstate[srow] = mnew;
        lstate[srow] = lstate[srow] * alpha + lloc;
        alpha_s[srow] = alpha;
      }
      u16x4 pw;
      pw[0] = f2bf(p0); pw[1] = f2bf(p1); pw[2] = f2bf(p2); pw[3] = f2bf(p3);
      *(u16x4*)&Pt[srow * 36 + ssub * 4] = pw;
    }
#pragma unroll
    for (int i = 0; i < 4; ++i) {
      int d0 = (dg + i * 16) * 8;
      u16x8 v0 = *(const u16x8*)(P + (kvb + kvp * 2) * LDQ + 1024 + d0);
      u16x8 v1 = *(const u16x8*)(P + (kvb + kvp * 2 + 1) * LDQ + 1024 + d0);
#pragma unroll
      for (int j = 0; j < 8; ++j) {
        u16x2 t2; t2[0] = v0[j]; t2[1] = v1[j];
        *(u16x2*)&KVs[(d0 + j) * 36 + kvp * 2] = t2;
      }
    }
    __syncthreads();

    float al[2][4];
#pragma unroll
    for (int mb = 0; mb < 2; ++mb)
#pragma unroll
      for (int r = 0; r < 4; ++r)
        al[mb][r] = alpha_s[mb * 16 + lg * 4 + r];
#pragma unroll
    for (int mb = 0; mb < 2; ++mb)
#pragma unroll
      for (int nb = 0; nb < 8; ++nb)
#pragma unroll
        for (int r = 0; r < 4; ++r)
          o[mb][nb][r] *= al[mb][r];

    bf16x8 pf[2];
#pragma unroll
    for (int mb = 0; mb < 2; ++mb) {
      u16x4 lo = *(const u16x4*)&Pt[(mb * 16 + l15) * 36 + lg * 8];
      u16x4 hi = *(const u16x4*)&Pt[(mb * 16 + l15) * 36 + lg * 8 + 4];
      pf[mb] = as_bf16x8(__builtin_shufflevector(lo, hi, 0, 1, 2, 3, 4, 5, 6, 7));
    }
#pragma unroll
    for (int nb = 0; nb < 8; ++nb) {
      int d = wbase + nb * 16 + l15;
      u16x4 lo = *(const u16x4*)&KVs[d * 36 + lg * 8];
      u16x4 hi = *(const u16x4*)&KVs[d * 36 + lg * 8 + 4];
      bf16x8 vf = as_bf16x8(__builtin_shufflevector(lo, hi, 0, 1, 2, 3, 4, 5, 6, 7));
#pragma unroll
      for (int mb = 0; mb < 2; ++mb)
        o[mb][nb] = __builtin_amdgcn_mfma_f32_16x16x32_bf16(pf[mb], vf, o[mb][nb], 0, 0, 0);
    }
    __syncthreads();
  }

  float li[2][4];
#pragma unroll
  for (int mb = 0; mb < 2; ++mb)
#pragma unroll
    for (int r = 0; r < 4; ++r)
      li[mb][r] = 1.0f / lstate[mb * 16 + lg * 4 + r];

  if (dir == 0) {
#pragma unroll
    for (int mb = 0; mb < 2; ++mb)
#pragma unroll
      for (int nb = 0; nb < 8; ++nb)
#pragma unroll
        for (int r = 0; r < 4; ++r)
          f1out[(qrow0 + mb * 16 + lg * 4 + r) * 512 + wbase + nb * 16 + l15] =
              f2bf(o[mb][nb][r] * li[mb][r]);
  } else {
    float g = g0;
#pragma unroll
    for (int mb = 0; mb < 2; ++mb)
#pragma unroll
      for (int nb = 0; nb < 8; ++nb)
#pragma unroll
        for (int r = 0; r < 4; ++r) {
          size_t idx = (qrow0 + mb * 16 + lg * 4 + r) * 512 + wbase + nb * 16 + l15;
          float f1v = bf2f(f1[idx]);
          float f2v = o[mb][nb][r] * li[mb][r];
          out32[idx] = g * (f1v + f2v) + bf2f(h1b[idx]) + bf2f(h2b[idx]);
        }
  }
}

// ---------- launch ----------
extern "C" void kernel_launch(void* const* d_in, const int* in_sizes, int n_in,
                              void* d_out, int out_size, void* d_ws, size_t ws_size,
                              hipStream_t stream)
{
  const float* x1    = (const float*)d_in[0];
  const float* x2    = (const float*)d_in[1];
  const float* Wp1   = (const float*)d_in[2];
  const float* bp1   = (const float*)d_in[3];
  const float* Wp2   = (const float*)d_in[4];
  const float* bp2   = (const float*)d_in[5];
  const float* Wq    = (const float*)d_in[6];
  const float* bq    = (const float*)d_in[7];
  const float* Wk    = (const float*)d_in[8];
  const float* bk    = (const float*)d_in[9];
  const float* Wv    = (const float*)d_in[10];
  const float* bv    = (const float*)d_in[11];
  const float* gamma = (const float*)d_in[12];
  float* out = (float*)d_out;
  char* ws = (char*)d_ws;

  unsigned short* WTp1 = (unsigned short*)(ws + 0);          // 512x768 bf16
  unsigned short* WTp2 = (unsigned short*)(ws + 786432);     // 512x1024 bf16
  unsigned short* WTq  = (unsigned short*)(ws + 1835008);    // 512x512 bf16
  unsigned short* WTk  = (unsigned short*)(ws + 2359296);
  unsigned short* WTv  = (unsigned short*)(ws + 2883584);
  unsigned short* h1b  = (unsigned short*)(ws + 3407872);    // 16384x512 bf16
  unsigned short* h2b  = (unsigned short*)(ws + 20185088);   // 16384x512 bf16
  unsigned short* f1b  = (unsigned short*)(ws + 36962304);   // 16384x512 bf16
  unsigned short* P1   = (unsigned short*)(ws + 53739520);   // 16384x1536 bf16

  // 1: all transposes, LDS-tiled (QKV segments gamma-gated inside)
  transpose_all_lds<<<416, 256, 0, stream>>>(Wp1, Wp2, Wq, Wk, Wv,
                                             WTp1, WTp2, WTq, WTk, WTv, gamma);

  // 2: gamma==0 fast path — the entire answer in one GEMM
  fused_h12_out<<<512, 256, 0, stream>>>(x1, x2, WTp1, WTp2, bp1, bp2, out, gamma);

  // 3: gamma!=0 path — h1/h2 bf16 (gated, merged z=2)
  gemm_h12<<<dim3(128, 4, 2), 256, 0, stream>>>(x1, x2, WTp1, WTp2, bp1, bp2, h1b, h2b, gamma);

  // 4-5: direction 0 QKV + attention (gated)
  gemm_qkv<<<dim3(128, 4, 3), 256, 0, stream>>>(h1b, h2b, WTq, WTk, WTv, bq, bk, bv, P1, gamma);
  flash_attn<<<dim3(64, 8), 256, 0, stream>>>(P1, f1b, h1b, h2b, gamma, f1b, out, 0);

  // 6-7: direction 1 QKV + attention/combine (gated)
  gemm_qkv<<<dim3(128, 4, 3), 256, 0, stream>>>(h2b, h1b, WTq, WTk, WTv, bq, bk, bv, P1, gamma);
  flash_attn<<<dim3(64, 8), 256, 0, stream>>>(P1, f1b, h1b, h2b, gamma, f1b, out, 1);
}

// Round 6
// 253.149 us; speedup vs baseline: 1.1325x; 1.1325x over previous
//
#include <hip/hip_runtime.h>
#include <stdint.h>

// Dtype model: inputs fp32, output fp32, internals bf16 MFMA.
// gamma == 0 in this instance => out = h1 + h2 = x1@Wp1 + x2@Wp2 + b1 + b2.
// R11: R10 regressed because it dropped R9's 2-deep A register pipeline
// (writeA stalled on same-iteration loads; 1 tile of MFMA << 900cy HBM).
// This round: COALESCED A loads (R10 mapping, 4 rows x 256B contiguous per
// wave-instr) + 2-deep static register banks arE/arO (R9 unroll-by-2
// schedule). XCD-group remap, XOR swizzle, BK=64 dbuf unchanged.

// ---------- types ----------
typedef __bf16 bf16x8 __attribute__((ext_vector_type(8)));
typedef float f32x4 __attribute__((ext_vector_type(4)));
typedef unsigned short u16x8 __attribute__((ext_vector_type(8)));
typedef unsigned short u16x4 __attribute__((ext_vector_type(4)));
typedef unsigned short u16x2 __attribute__((ext_vector_type(2)));

typedef __attribute__((address_space(3))) unsigned int as3_u32;
typedef const __attribute__((address_space(1))) unsigned int as1_u32;

__device__ __forceinline__ float bf2f(unsigned short h) {
  union { unsigned int u; float f; } v; v.u = ((unsigned int)h) << 16; return v.f;
}
__device__ __forceinline__ unsigned short f2bf(float f) {
  union { float f; unsigned int u; } v; v.f = f;
  unsigned int u = v.u;
  return (unsigned short)((u + 0x7fffu + ((u >> 16) & 1u)) >> 16);
}
__device__ __forceinline__ bf16x8 as_bf16x8(u16x8 x) {
  union { u16x8 u; bf16x8 b; } c; c.u = x; return c.b;
}
// async global->LDS, 16B per lane; lds base must be wave-uniform
__device__ __forceinline__ void async_load16(unsigned short* lds, const unsigned short* g) {
  __builtin_amdgcn_global_load_lds((as1_u32*)g, (as3_u32*)lds, 16, 0, 0);
}

// ---------- LDS-tiled weight transpose: dst_bf16[512][K] = src_f32[K][512] ----------
__global__ __launch_bounds__(256) void transpose_all_lds(
    const float* __restrict__ Wp1, const float* __restrict__ Wp2,
    const float* __restrict__ Wq, const float* __restrict__ Wk,
    const float* __restrict__ Wv,
    unsigned short* __restrict__ o1, unsigned short* __restrict__ o2,
    unsigned short* __restrict__ oq, unsigned short* __restrict__ ok,
    unsigned short* __restrict__ ov,
    const float* __restrict__ gamma)
{
  __shared__ unsigned short sT[64][72];  // [n][k], stride 144B (16B-aligned)
  const int bid = blockIdx.x;
  const int tid = threadIdx.x;

  const float* src; unsigned short* dst; int K, ktiles, base;
  if (bid < 96)       { src = Wp1; dst = o1; K = 768;  ktiles = 12; base = 0; }
  else if (bid < 224) { src = Wp2; dst = o2; K = 1024; ktiles = 16; base = 96; }
  else {
    if (gamma[0] == 0.0f) return;  // QKV weights only feed attention
    K = 512; ktiles = 8;
    if (bid < 288)      { src = Wq; dst = oq; base = 224; }
    else if (bid < 352) { src = Wk; dst = ok; base = 288; }
    else                { src = Wv; dst = ov; base = 352; }
  }
  const int local = bid - base;
  const int k0 = (local % ktiles) * 64;
  const int n0 = (local / ktiles) * 64;

  const int rr = tid >> 4, c4 = tid & 15;
#pragma unroll
  for (int i = 0; i < 4; ++i) {
    int row = i * 16 + rr;
    f32x4 v = *(const f32x4*)(src + (size_t)(k0 + row) * 512 + n0 + c4 * 4);
#pragma unroll
    for (int j = 0; j < 4; ++j)
      sT[c4 * 4 + j][row] = f2bf(v[j]);
  }
  __syncthreads();

  const int nr = tid >> 3, kq = tid & 7;
#pragma unroll
  for (int i = 0; i < 2; ++i) {
    int n = i * 32 + nr;
    *(u16x8*)(dst + (size_t)(n0 + n) * K + k0 + kq * 8) = *(const u16x8*)&sT[n][kq * 8];
  }
}

// ---------- fused gamma==0 output GEMM ----------
// out_f32[16384,512] = x1@Wp1 + x2@Wp2 + b1 + b2, K = 768+1024 = 1792.
// 128x128 tile, BK=64, dbuf LDS, XOR swizzle, XCD-group remap, coalesced A
// staging, 2-deep A register pipeline (static banks, unroll-by-2).
__global__ __launch_bounds__(256) void fused_h12_out(
    const float* __restrict__ x1, const float* __restrict__ x2,
    const unsigned short* __restrict__ WT1, const unsigned short* __restrict__ WT2,
    const float* __restrict__ b1, const float* __restrict__ b2,
    float* __restrict__ out, const float* __restrict__ gamma)
{
  if (gamma[0] != 0.0f) return;  // gamma!=0 handled by the full path
  __shared__ __align__(16) unsigned short sA[2][128 * 64];
  __shared__ __align__(16) unsigned short sB[2][128 * 64];
  const int tid = threadIdx.x;
  const int lane = tid & 63;
  const int w = tid >> 6;
  const int wm = w & 1, wn = w >> 1;
  const int l15 = lane & 15, lg = lane >> 4;

  const int f = blockIdx.x;                     // 0..511
  const int bx = (f >> 3) & 3;                  // col tile (4)
  const int by = (f & 7) | ((f >> 5) << 3);     // row panel (128); same-panel
                                                // quads share f%8 -> same XCD
  const size_t row0A = (size_t)by * 128;
  const int row0B = bx * 128;

  f32x4 arE[8], arO[8];                         // 2-deep A prefetch banks
  f32x4 acc[4][4] = {};

  // A tile 128x64 f32 = 2048 f32x4 chunks; thread does 8, coalesced:
  // chunk cc=i*256+tid -> row=cc>>4 (16 chunks/row), c4=cc&15.
  auto loadA = [&](int kk, f32x4 (&ar)[8]) {
#pragma unroll
    for (int i = 0; i < 8; ++i) {
      int cc = i * 256 + tid;
      int row = cc >> 4, c4 = cc & 15;
      const float* ap = (kk < 768)
          ? (x1 + (row0A + row) * 768 + kk + c4 * 4)
          : (x2 + (row0A + row) * 1024 + (kk - 768) + c4 * 4);
      ar[i] = *(const f32x4*)ap;
    }
  };
  // B tile = 128 rows x 64 bf16 = 1024 16B chunks -> 4 chunks/thread.
  auto stageB = [&](int kk, int buf) {
#pragma unroll
    for (int j = 0; j < 4; ++j) {
      int cc = (w * 4 + j) * 64 + lane;      // 16B chunk id 0..1023
      int r = cc >> 3, c = cc & 7;
      int cs = c ^ (r & 7);                  // pre-swizzled global source
      const unsigned short* bp = (kk < 768)
          ? (WT1 + (size_t)(row0B + r) * 768 + kk + cs * 8)
          : (WT2 + (size_t)(row0B + r) * 1024 + (kk - 768) + cs * 8);
      async_load16(&sB[buf][(size_t)(w * 4 + j) * 512], bp);
    }
  };
  // convert + swizzled ds_write_b64: logical 16B-chunk c=c4>>1, half=c4&1.
  auto writeA = [&](int buf, const f32x4 (&ar)[8]) {
#pragma unroll
    for (int i = 0; i < 8; ++i) {
      int cc = i * 256 + tid;
      int row = cc >> 4, c4 = cc & 15;
      int c = c4 >> 1, half = c4 & 1;
      u16x4 hv;
#pragma unroll
      for (int j = 0; j < 4; ++j) hv[j] = f2bf(ar[i][j]);
      *(u16x4*)&sA[buf][row * 64 + ((c ^ (row & 7)) << 3) + (half << 2)] = hv;
    }
  };
  auto compute = [&](int buf) {
#pragma unroll
    for (int ks = 0; ks < 2; ++ks) {
      bf16x8 af[4], bfr[4];
#pragma unroll
      for (int mb = 0; mb < 4; ++mb) {
        int row = wm * 64 + mb * 16 + l15;
        int cs = (ks * 4 + lg) ^ (row & 7);
        af[mb] = *(const bf16x8*)&sA[buf][row * 64 + cs * 8];
      }
#pragma unroll
      for (int nb = 0; nb < 4; ++nb) {
        int row = wn * 64 + nb * 16 + l15;
        int cs = (ks * 4 + lg) ^ (row & 7);
        bfr[nb] = *(const bf16x8*)&sB[buf][row * 64 + cs * 8];
      }
#pragma unroll
      for (int mb = 0; mb < 4; ++mb)
#pragma unroll
        for (int nb = 0; nb < 4; ++nb)
          acc[mb][nb] = __builtin_amdgcn_mfma_f32_16x16x32_bf16(af[mb], bfr[nb], acc[mb][nb], 0, 0, 0);
    }
  };

  // prologue: tile 0 staged; tile 1's A issued (2-deep from iter 0 onward)
  loadA(0, arE);
  stageB(0, 0);
  writeA(0, arE);
  loadA(64, arO);
  __syncthreads();

  const int NT = 28;  // 1792 / 64
  // invariant at top of iter t (cur = t&1): sA/sB[cur] ready; the bank
  // written by the PREVIOUS iteration's loadA holds A(t+1); writeA for
  // buf cur^1 consumes loads issued a full iteration ago (latency covered).
  int cur = 0;
  for (int t = 0; t < NT; t += 2) {
    // even iter t: compute cur; A(t+2) -> arE; write A(t+1) from arO
    if (t + 1 < NT) stageB((t + 1) * 64, cur ^ 1);
    if (t + 2 < NT) loadA((t + 2) * 64, arE);
    compute(cur);
    if (t + 1 < NT) writeA(cur ^ 1, arO);
    __syncthreads();
    cur ^= 1;
    // odd iter t+1: compute cur; A(t+3) -> arO; write A(t+2) from arE
    if (t + 1 < NT) {
      if (t + 2 < NT) stageB((t + 2) * 64, cur ^ 1);
      if (t + 3 < NT) loadA((t + 3) * 64, arO);
      compute(cur);
      if (t + 2 < NT) writeA(cur ^ 1, arE);
      __syncthreads();
      cur ^= 1;
    }
  }

  // epilogue: fp32 direct store, bias = b1 + b2
  const int colb = row0B + wn * 64;
#pragma unroll
  for (int nb = 0; nb < 4; ++nb) {
    int col = colb + nb * 16 + l15;
    float bv = b1[col] + b2[col];
#pragma unroll
    for (int mb = 0; mb < 4; ++mb) {
      size_t rowb = row0A + wm * 64 + mb * 16 + lg * 4;
#pragma unroll
      for (int r = 0; r < 4; ++r)
        out[(rowb + r) * 512 + col] = acc[mb][nb][r] + bv;
    }
  }
}

// ---------- gated h-GEMMs (gamma!=0 path): z=0 -> h1, z=1 -> h2 ----------
__global__ __launch_bounds__(256) void gemm_h12(
    const float* __restrict__ x1, const float* __restrict__ x2,
    const unsigned short* __restrict__ WT1, const unsigned short* __restrict__ WT2,
    const float* __restrict__ b1, const float* __restrict__ b2,
    unsigned short* __restrict__ h1b, unsigned short* __restrict__ h2b,
    const float* __restrict__ gate)
{
  if (gate[0] == 0.0f) return;
  const int z = blockIdx.z;
  const float* A = z ? x2 : x1;
  const unsigned short* Bt = z ? WT2 : WT1;
  const float* bias = z ? b2 : b1;
  unsigned short* C = z ? h2b : h1b;
  const int K = z ? 1024 : 768;
  const int ldc = 512;

  __shared__ __align__(16) unsigned short sA[128 * 32];
  __shared__ __align__(16) unsigned short sB[128 * 32];
  const int tid = threadIdx.x;
  const int lane = tid & 63;
  const int w = tid >> 6;
  const int wm = w & 1, wn = w >> 1;
  const int l15 = lane & 15, lg = lane >> 4;
  const size_t row0A = (size_t)blockIdx.x * 128;
  const size_t row0B = (size_t)blockIdx.y * 128;
  f32x4 acc[4][4] = {};

  for (int kb = 0; kb < K; kb += 32) {
#pragma unroll
    for (int j = 0; j < 2; ++j) {
      int cc = (w * 2 + j) * 64 + lane;
      int r = cc >> 2, k8 = cc & 3;
      async_load16(&sB[(size_t)((w * 2 + j) * 64) * 8], Bt + (row0B + r) * K + kb + k8 * 8);
    }
    {
      // coalesced A staging: 128x32 f32 tile = 1024 f32x4 chunks, 4/thread
#pragma unroll
      for (int i = 0; i < 4; ++i) {
        int cc = i * 256 + tid;
        int row = cc >> 3, c4 = cc & 7;     // 8 chunks per 32-float row
        f32x4 v = *(const f32x4*)(A + (row0A + row) * K + kb + c4 * 4);
        u16x4 hv;
#pragma unroll
        for (int j = 0; j < 4; ++j) hv[j] = f2bf(v[j]);
        *(u16x4*)&sA[row * 32 + c4 * 4] = hv;
      }
    }
    __syncthreads();
    bf16x8 af[4], bfr[4];
#pragma unroll
    for (int mb = 0; mb < 4; ++mb)
      af[mb] = *(const bf16x8*)&sA[(wm * 64 + mb * 16 + l15) * 32 + lg * 8];
#pragma unroll
    for (int nb = 0; nb < 4; ++nb)
      bfr[nb] = *(const bf16x8*)&sB[(wn * 64 + nb * 16 + l15) * 32 + lg * 8];
#pragma unroll
    for (int mb = 0; mb < 4; ++mb)
#pragma unroll
      for (int nb = 0; nb < 4; ++nb)
        acc[mb][nb] = __builtin_amdgcn_mfma_f32_16x16x32_bf16(af[mb], bfr[nb], acc[mb][nb], 0, 0, 0);
    __syncthreads();
  }

  const int colb = (int)row0B + wn * 64;
#pragma unroll
  for (int nb = 0; nb < 4; ++nb) {
    int col = colb + nb * 16 + l15;
    float bv = bias[col];
#pragma unroll
    for (int mb = 0; mb < 4; ++mb) {
      size_t rowb = row0A + wm * 64 + mb * 16 + lg * 4;
#pragma unroll
      for (int r = 0; r < 4; ++r)
        C[(rowb + r) * ldc + col] = f2bf(acc[mb][nb][r] + bv);
    }
  }
}

// ---------- QKV projections: 3 GEMMs in one launch via blockIdx.z ----------
__global__ __launch_bounds__(256) void gemm_qkv(
    const unsigned short* __restrict__ Aq,
    const unsigned short* __restrict__ Akv,
    const unsigned short* __restrict__ Wq_, const unsigned short* __restrict__ Wk_,
    const unsigned short* __restrict__ Wv_,
    const float* __restrict__ bq_, const float* __restrict__ bk_,
    const float* __restrict__ bv_,
    unsigned short* __restrict__ P,
    const float* __restrict__ gate)
{
  if (gate[0] == 0.0f) return;
  const int z = blockIdx.z;
  const unsigned short* A  = (z == 0) ? Aq : Akv;
  const unsigned short* Bt = (z == 0) ? Wq_ : (z == 1 ? Wk_ : Wv_);
  const float* bias        = (z == 0) ? bq_ : (z == 1 ? bk_ : bv_);
  unsigned short* C = P + z * 512;
  const int K = 512, ldc = 1536;

  __shared__ __align__(16) unsigned short sA[128 * 32];
  __shared__ __align__(16) unsigned short sB[128 * 32];
  const int tid = threadIdx.x;
  const int lane = tid & 63;
  const int w = tid >> 6;
  const int wm = w & 1, wn = w >> 1;
  const int l15 = lane & 15, lg = lane >> 4;
  const size_t row0A = (size_t)blockIdx.x * 128;
  const size_t row0B = (size_t)blockIdx.y * 128;
  f32x4 acc[4][4] = {};

  for (int kb = 0; kb < K; kb += 32) {
#pragma unroll
    for (int j = 0; j < 2; ++j) {
      int cc = (w * 2 + j) * 64 + lane;
      int r = cc >> 2, k8 = cc & 3;
      async_load16(&sA[(size_t)((w * 2 + j) * 64) * 8], A + (row0A + r) * K + kb + k8 * 8);
      async_load16(&sB[(size_t)((w * 2 + j) * 64) * 8], Bt + (row0B + r) * K + kb + k8 * 8);
    }
    __syncthreads();
    bf16x8 af[4], bfr[4];
#pragma unroll
    for (int mb = 0; mb < 4; ++mb)
      af[mb] = *(const bf16x8*)&sA[(wm * 64 + mb * 16 + l15) * 32 + lg * 8];
#pragma unroll
    for (int nb = 0; nb < 4; ++nb)
      bfr[nb] = *(const bf16x8*)&sB[(wn * 64 + nb * 16 + l15) * 32 + lg * 8];
#pragma unroll
    for (int mb = 0; mb < 4; ++mb)
#pragma unroll
      for (int nb = 0; nb < 4; ++nb)
        acc[mb][nb] = __builtin_amdgcn_mfma_f32_16x16x32_bf16(af[mb], bfr[nb], acc[mb][nb], 0, 0, 0);
    __syncthreads();
  }

  const int colb = (int)row0B + wn * 64;
#pragma unroll
  for (int nb = 0; nb < 4; ++nb) {
    int col = colb + nb * 16 + l15;
    float bv = bias[col];
#pragma unroll
    for (int mb = 0; mb < 4; ++mb) {
      size_t rowb = row0A + wm * 64 + mb * 16 + lg * 4;
#pragma unroll
      for (int r = 0; r < 4; ++r)
        C[(rowb + r) * ldc + col] = f2bf(acc[mb][nb][r] + bv);
    }
  }
}

// ---------- flash attention (gamma!=0 path; gamma==0 -> no-op) ----------
#define LDQ 1536
__global__ __launch_bounds__(256) void flash_attn(
    const unsigned short* __restrict__ P,
    const unsigned short* __restrict__ f1,
    const unsigned short* __restrict__ h1b,
    const unsigned short* __restrict__ h2b,
    const float* __restrict__ gamma,
    unsigned short* __restrict__ f1out,
    float* __restrict__ out32,
    int dir)
{
  const float g0 = gamma[0];
  if (g0 == 0.0f) return;  // fused_h12_out already wrote the final output

  __shared__ __align__(16) unsigned short KVs[18432];
  __shared__ __align__(16) float Sred[4608];
  __shared__ __align__(16) unsigned short Pt[1152];
  __shared__ float mstate[32], lstate[32], alpha_s[32];

  const int tid = threadIdx.x;
  const int lane = tid & 63;
  const int w = tid >> 6;
  const int l15 = lane & 15, lg = lane >> 4;
  const int wbase = w * 128;
  const int qt = blockIdx.x;
  const int b = blockIdx.y;
  const size_t qrow0 = (size_t)b * 2048 + (size_t)qt * 32;
  const size_t krow0 = (size_t)b * 2048;

  if (tid < 32) { mstate[tid] = -1e30f; lstate[tid] = 0.f; }
  __syncthreads();

  bf16x8 qf[2][4];
#pragma unroll
  for (int mb = 0; mb < 2; ++mb)
#pragma unroll
    for (int ks = 0; ks < 4; ++ks)
      qf[mb][ks] = *(const bf16x8*)(P + (qrow0 + mb * 16 + l15) * LDQ + wbase + ks * 32 + lg * 8);

  f32x4 o[2][8] = {};

  const int srow = tid >> 3, ssub = tid & 7;
  const int kvp = tid & 15, dg = tid >> 4;

  for (int kt = 0; kt < 64; ++kt) {
    const size_t kvb = krow0 + (size_t)kt * 32;
#pragma unroll
    for (int i = 0; i < 8; ++i) {
      int cc = tid + i * 256;
      int r = cc >> 6, c8 = cc & 63;
      *(u16x8*)&KVs[r * 520 + c8 * 8] = *(const u16x8*)(P + (kvb + r) * LDQ + 512 + c8 * 8);
    }
    __syncthreads();

    f32x4 sacc[2][2] = {};
#pragma unroll
    for (int ks = 0; ks < 4; ++ks)
#pragma unroll
      for (int nb = 0; nb < 2; ++nb) {
        bf16x8 kf = *(const bf16x8*)&KVs[(nb * 16 + l15) * 520 + wbase + ks * 32 + lg * 8];
#pragma unroll
        for (int mb = 0; mb < 2; ++mb)
          sacc[mb][nb] = __builtin_amdgcn_mfma_f32_16x16x32_bf16(qf[mb][ks], kf, sacc[mb][nb], 0, 0, 0);
      }
#pragma unroll
    for (int mb = 0; mb < 2; ++mb)
#pragma unroll
      for (int nb = 0; nb < 2; ++nb)
#pragma unroll
        for (int r = 0; r < 4; ++r)
          Sred[w * 1152 + (mb * 16 + lg * 4 + r) * 36 + nb * 16 + l15] = sacc[mb][nb][r];
    __syncthreads();

    {
      f32x4 sv = {};
#pragma unroll
      for (int w2 = 0; w2 < 4; ++w2)
        sv += *(const f32x4*)&Sred[w2 * 1152 + srow * 36 + ssub * 4];
      const float scale = 0.044194173824159216f;
      sv *= scale;
      float mloc = fmaxf(fmaxf(sv[0], sv[1]), fmaxf(sv[2], sv[3]));
      mloc = fmaxf(mloc, __shfl_xor(mloc, 1));
      mloc = fmaxf(mloc, __shfl_xor(mloc, 2));
      mloc = fmaxf(mloc, __shfl_xor(mloc, 4));
      float mold = mstate[srow];
      float mnew = fmaxf(mold, mloc);
      const float LOG2E = 1.4426950408889634f;
      float p0 = exp2f((sv[0] - mnew) * LOG2E);
      float p1 = exp2f((sv[1] - mnew) * LOG2E);
      float p2 = exp2f((sv[2] - mnew) * LOG2E);
      float p3 = exp2f((sv[3] - mnew) * LOG2E);
      float lloc = p0 + p1 + p2 + p3;
      lloc += __shfl_xor(lloc, 1);
      lloc += __shfl_xor(lloc, 2);
      lloc += __shfl_xor(lloc, 4);
      float alpha = exp2f((mold - mnew) * LOG2E);
      if (ssub == 0) {
        mstate[srow] = mnew;
        lstate[srow] = lstate[srow] * alpha + lloc;
        alpha_s[srow] = alpha;
      }
      u16x4 pw;
      pw[0] = f2bf(p0); pw[1] = f2bf(p1); pw[2] = f2bf(p2); pw[3] = f2bf(p3);
      *(u16x4*)&Pt[srow * 36 + ssub * 4] = pw;
    }
#pragma unroll
    for (int i = 0; i < 4; ++i) {
      int d0 = (dg + i * 16) * 8;
      u16x8 v0 = *(const u16x8*)(P + (kvb + kvp * 2) * LDQ + 1024 + d0);
      u16x8 v1 = *(const u16x8*)(P + (kvb + kvp * 2 + 1) * LDQ + 1024 + d0);
#pragma unroll
      for (int j = 0; j < 8; ++j) {
        u16x2 t2; t2[0] = v0[j]; t2[1] = v1[j];
        *(u16x2*)&KVs[(d0 + j) * 36 + kvp * 2] = t2;
      }
    }
    __syncthreads();

    float al[2][4];
#pragma unroll
    for (int mb = 0; mb < 2; ++mb)
#pragma unroll
      for (int r = 0; r < 4; ++r)
        al[mb][r] = alpha_s[mb * 16 + lg * 4 + r];
#pragma unroll
    for (int mb = 0; mb < 2; ++mb)
#pragma unroll
      for (int nb = 0; nb < 8; ++nb)
#pragma unroll
        for (int r = 0; r < 4; ++r)
          o[mb][nb][r] *= al[mb][r];

    bf16x8 pf[2];
#pragma unroll
    for (int mb = 0; mb < 2; ++mb) {
      u16x4 lo = *(const u16x4*)&Pt[(mb * 16 + l15) * 36 + lg * 8];
      u16x4 hi = *(const u16x4*)&Pt[(mb * 16 + l15) * 36 + lg * 8 + 4];
      pf[mb] = as_bf16x8(__builtin_shufflevector(lo, hi, 0, 1, 2, 3, 4, 5, 6, 7));
    }
#pragma unroll
    for (int nb = 0; nb < 8; ++nb) {
      int d = wbase + nb * 16 + l15;
      u16x4 lo = *(const u16x4*)&KVs[d * 36 + lg * 8];
      u16x4 hi = *(const u16x4*)&KVs[d * 36 + lg * 8 + 4];
      bf16x8 vf = as_bf16x8(__builtin_shufflevector(lo, hi, 0, 1, 2, 3, 4, 5, 6, 7));
#pragma unroll
      for (int mb = 0; mb < 2; ++mb)
        o[mb][nb] = __builtin_amdgcn_mfma_f32_16x16x32_bf16(pf[mb], vf, o[mb][nb], 0, 0, 0);
    }
    __syncthreads();
  }

  float li[2][4];
#pragma unroll
  for (int mb = 0; mb < 2; ++mb)
#pragma unroll
    for (int r = 0; r < 4; ++r)
      li[mb][r] = 1.0f / lstate[mb * 16 + lg * 4 + r];

  if (dir == 0) {
#pragma unroll
    for (int mb = 0; mb < 2; ++mb)
#pragma unroll
      for (int nb = 0; nb < 8; ++nb)
#pragma unroll
        for (int r = 0; r < 4; ++r)
          f1out[(qrow0 + mb * 16 + lg * 4 + r) * 512 + wbase + nb * 16 + l15] =
              f2bf(o[mb][nb][r] * li[mb][r]);
  } else {
    float g = g0;
#pragma unroll
    for (int mb = 0; mb < 2; ++mb)
#pragma unroll
      for (int nb = 0; nb < 8; ++nb)
#pragma unroll
        for (int r = 0; r < 4; ++r) {
          size_t idx = (qrow0 + mb * 16 + lg * 4 + r) * 512 + wbase + nb * 16 + l15;
          float f1v = bf2f(f1[idx]);
          float f2v = o[mb][nb][r] * li[mb][r];
          out32[idx] = g * (f1v + f2v) + bf2f(h1b[idx]) + bf2f(h2b[idx]);
        }
  }
}

// ---------- launch ----------
extern "C" void kernel_launch(void* const* d_in, const int* in_sizes, int n_in,
                              void* d_out, int out_size, void* d_ws, size_t ws_size,
                              hipStream_t stream)
{
  const float* x1    = (const float*)d_in[0];
  const float* x2    = (const float*)d_in[1];
  const float* Wp1   = (const float*)d_in[2];
  const float* bp1   = (const float*)d_in[3];
  const float* Wp2   = (const float*)d_in[4];
  const float* bp2   = (const float*)d_in[5];
  const float* Wq    = (const float*)d_in[6];
  const float* bq    = (const float*)d_in[7];
  const float* Wk    = (const float*)d_in[8];
  const float* bk    = (const float*)d_in[9];
  const float* Wv    = (const float*)d_in[10];
  const float* bv    = (const float*)d_in[11];
  const float* gamma = (const float*)d_in[12];
  float* out = (float*)d_out;
  char* ws = (char*)d_ws;

  unsigned short* WTp1 = (unsigned short*)(ws + 0);          // 512x768 bf16
  unsigned short* WTp2 = (unsigned short*)(ws + 786432);     // 512x1024 bf16
  unsigned short* WTq  = (unsigned short*)(ws + 1835008);    // 512x512 bf16
  unsigned short* WTk  = (unsigned short*)(ws + 2359296);
  unsigned short* WTv  = (unsigned short*)(ws + 2883584);
  unsigned short* h1b  = (unsigned short*)(ws + 3407872);    // 16384x512 bf16
  unsigned short* h2b  = (unsigned short*)(ws + 20185088);   // 16384x512 bf16
  unsigned short* f1b  = (unsigned short*)(ws + 36962304);   // 16384x512 bf16
  unsigned short* P1   = (unsigned short*)(ws + 53739520);   // 16384x1536 bf16

  // 1: all transposes, LDS-tiled (QKV segments gamma-gated inside)
  transpose_all_lds<<<416, 256, 0, stream>>>(Wp1, Wp2, Wq, Wk, Wv,
                                             WTp1, WTp2, WTq, WTk, WTv, gamma);

  // 2: gamma==0 fast path — the entire answer in one GEMM
  fused_h12_out<<<512, 256, 0, stream>>>(x1, x2, WTp1, WTp2, bp1, bp2, out, gamma);

  // 3: gamma!=0 path — h1/h2 bf16 (gated, merged z=2)
  gemm_h12<<<dim3(128, 4, 2), 256, 0, stream>>>(x1, x2, WTp1, WTp2, bp1, bp2, h1b, h2b, gamma);

  // 4-5: direction 0 QKV + attention (gated)
  gemm_qkv<<<dim3(128, 4, 3), 256, 0, stream>>>(h1b, h2b, WTq, WTk, WTv, bq, bk, bv, P1, gamma);
  flash_attn<<<dim3(64, 8), 256, 0, stream>>>(P1, f1b, h1b, h2b, gamma, f1b, out, 0);

  // 6-7: direction 1 QKV + attention/combine (gated)
  gemm_qkv<<<dim3(128, 4, 3), 256, 0, stream>>>(h2b, h1b, WTq, WTk, WTv, bq, bk, bv, P1, gamma);
  flash_attn<<<dim3(64, 8), 256, 0, stream>>>(P1, f1b, h1b, h2b, gamma, f1b, out, 1);
}

// Round 7
// 231.901 us; speedup vs baseline: 1.2362x; 1.0916x over previous
//
#include <hip/hip_runtime.h>
#include <stdint.h>

// Dtype model: inputs fp32, output fp32, internals bf16 MFMA.
// gamma == 0 in this instance => out = h1 + h2 = x1@Wp1 + x2@Wp2 + b1 + b2.
// R12: R9-R11 showed the 128x128-tile fused GEMM is pinned at 2 blocks/CU
// (occupancy 11-21%, all pipes idle) — the per-iteration barrier drains
// freshly-issued HBM loads with nothing to overlap. Fix via TLP: 64x64 tile,
// BK=64, dbuf LDS = 32 KiB -> 5 blocks/CU (5x32KiB = 160KiB exact),
// __launch_bounds__(256,5). Grid 2048, remap bx=f>>8/by=f&255 so the 8
// col-sharers of an A-panel share f%8 -> same XCD L2. Staging = verified
// coalesced+XOR-swizzle pattern, 1-deep (TLP covers latency now).

// ---------- types ----------
typedef __bf16 bf16x8 __attribute__((ext_vector_type(8)));
typedef float f32x4 __attribute__((ext_vector_type(4)));
typedef unsigned short u16x8 __attribute__((ext_vector_type(8)));
typedef unsigned short u16x4 __attribute__((ext_vector_type(4)));
typedef unsigned short u16x2 __attribute__((ext_vector_type(2)));

typedef __attribute__((address_space(3))) unsigned int as3_u32;
typedef const __attribute__((address_space(1))) unsigned int as1_u32;

__device__ __forceinline__ float bf2f(unsigned short h) {
  union { unsigned int u; float f; } v; v.u = ((unsigned int)h) << 16; return v.f;
}
__device__ __forceinline__ unsigned short f2bf(float f) {
  union { float f; unsigned int u; } v; v.f = f;
  unsigned int u = v.u;
  return (unsigned short)((u + 0x7fffu + ((u >> 16) & 1u)) >> 16);
}
__device__ __forceinline__ bf16x8 as_bf16x8(u16x8 x) {
  union { u16x8 u; bf16x8 b; } c; c.u = x; return c.b;
}
// async global->LDS, 16B per lane; lds base must be wave-uniform
__device__ __forceinline__ void async_load16(unsigned short* lds, const unsigned short* g) {
  __builtin_amdgcn_global_load_lds((as1_u32*)g, (as3_u32*)lds, 16, 0, 0);
}

// ---------- LDS-tiled weight transpose: dst_bf16[512][K] = src_f32[K][512] ----------
__global__ __launch_bounds__(256) void transpose_all_lds(
    const float* __restrict__ Wp1, const float* __restrict__ Wp2,
    const float* __restrict__ Wq, const float* __restrict__ Wk,
    const float* __restrict__ Wv,
    unsigned short* __restrict__ o1, unsigned short* __restrict__ o2,
    unsigned short* __restrict__ oq, unsigned short* __restrict__ ok,
    unsigned short* __restrict__ ov,
    const float* __restrict__ gamma)
{
  __shared__ unsigned short sT[64][72];  // [n][k], stride 144B (16B-aligned)
  const int bid = blockIdx.x;
  const int tid = threadIdx.x;

  const float* src; unsigned short* dst; int K, ktiles, base;
  if (bid < 96)       { src = Wp1; dst = o1; K = 768;  ktiles = 12; base = 0; }
  else if (bid < 224) { src = Wp2; dst = o2; K = 1024; ktiles = 16; base = 96; }
  else {
    if (gamma[0] == 0.0f) return;  // QKV weights only feed attention
    K = 512; ktiles = 8;
    if (bid < 288)      { src = Wq; dst = oq; base = 224; }
    else if (bid < 352) { src = Wk; dst = ok; base = 288; }
    else                { src = Wv; dst = ov; base = 352; }
  }
  const int local = bid - base;
  const int k0 = (local % ktiles) * 64;
  const int n0 = (local / ktiles) * 64;

  const int rr = tid >> 4, c4 = tid & 15;
#pragma unroll
  for (int i = 0; i < 4; ++i) {
    int row = i * 16 + rr;
    f32x4 v = *(const f32x4*)(src + (size_t)(k0 + row) * 512 + n0 + c4 * 4);
#pragma unroll
    for (int j = 0; j < 4; ++j)
      sT[c4 * 4 + j][row] = f2bf(v[j]);
  }
  __syncthreads();

  const int nr = tid >> 3, kq = tid & 7;
#pragma unroll
  for (int i = 0; i < 2; ++i) {
    int n = i * 32 + nr;
    *(u16x8*)(dst + (size_t)(n0 + n) * K + k0 + kq * 8) = *(const u16x8*)&sT[n][kq * 8];
  }
}

// ---------- fused gamma==0 output GEMM ----------
// out_f32[16384,512] = x1@Wp1 + x2@Wp2 + b1 + b2, K = 768+1024 = 1792.
// 64x64 tile, BK=64, dbuf LDS (32 KiB -> 5 blocks/CU), XOR swizzle,
// grid 2048: bx=f>>8 (8 col tiles), by=f&255 (256 row panels); the 8
// col-sharers of panel `by` share f%8=by%8 -> same XCD L2.
__global__ __launch_bounds__(256, 5) void fused_h12_out(
    const float* __restrict__ x1, const float* __restrict__ x2,
    const unsigned short* __restrict__ WT1, const unsigned short* __restrict__ WT2,
    const float* __restrict__ b1, const float* __restrict__ b2,
    float* __restrict__ out, const float* __restrict__ gamma)
{
  if (gamma[0] != 0.0f) return;  // gamma!=0 handled by the full path
  __shared__ __align__(16) unsigned short sA[2][64 * 64];
  __shared__ __align__(16) unsigned short sB[2][64 * 64];
  const int tid = threadIdx.x;
  const int lane = tid & 63;
  const int w = tid >> 6;
  const int wm = w & 1, wn = w >> 1;
  const int l15 = lane & 15, lg = lane >> 4;

  const int f = blockIdx.x;                 // 0..2047
  const int bx = f >> 8;                    // col tile 0..7
  const int by = f & 255;                   // row panel 0..255
  const size_t row0A = (size_t)by * 64;
  const int row0B = bx * 64;

  f32x4 ar[4];
  f32x4 acc[2][2] = {};

  // A tile 64x64 f32 = 1024 f32x4 chunks; 4/thread, coalesced:
  // cc = i*256+tid -> row = cc>>4 (16 chunks/row), c4 = cc&15.
  auto loadA = [&](int kk) {
#pragma unroll
    for (int i = 0; i < 4; ++i) {
      int cc = i * 256 + tid;
      int row = cc >> 4, c4 = cc & 15;
      const float* ap = (kk < 768)
          ? (x1 + (row0A + row) * 768 + kk + c4 * 4)
          : (x2 + (row0A + row) * 1024 + (kk - 768) + c4 * 4);
      ar[i] = *(const f32x4*)ap;
    }
  };
  // B tile = 64 rows x 64 bf16 = 512 16B chunks -> 2/thread.
  auto stageB = [&](int kk, int buf) {
#pragma unroll
    for (int j = 0; j < 2; ++j) {
      int cc = (w * 2 + j) * 64 + lane;      // 16B chunk id 0..511
      int r = cc >> 3, c = cc & 7;
      int cs = c ^ (r & 7);                  // pre-swizzled global source
      const unsigned short* bp = (kk < 768)
          ? (WT1 + (size_t)(row0B + r) * 768 + kk + cs * 8)
          : (WT2 + (size_t)(row0B + r) * 1024 + (kk - 768) + cs * 8);
      async_load16(&sB[buf][(size_t)(w * 2 + j) * 512], bp);
    }
  };
  // convert + swizzled ds_write_b64: logical 16B-chunk c=c4>>1, half=c4&1.
  auto writeA = [&](int buf) {
#pragma unroll
    for (int i = 0; i < 4; ++i) {
      int cc = i * 256 + tid;
      int row = cc >> 4, c4 = cc & 15;
      int c = c4 >> 1, half = c4 & 1;
      u16x4 hv;
#pragma unroll
      for (int j = 0; j < 4; ++j) hv[j] = f2bf(ar[i][j]);
      *(u16x4*)&sA[buf][row * 64 + ((c ^ (row & 7)) << 3) + (half << 2)] = hv;
    }
  };
  auto compute = [&](int buf) {
#pragma unroll
    for (int ks = 0; ks < 2; ++ks) {
      bf16x8 af[2], bfr[2];
#pragma unroll
      for (int mb = 0; mb < 2; ++mb) {
        int row = wm * 32 + mb * 16 + l15;
        int cs = (ks * 4 + lg) ^ (row & 7);
        af[mb] = *(const bf16x8*)&sA[buf][row * 64 + cs * 8];
      }
#pragma unroll
      for (int nb = 0; nb < 2; ++nb) {
        int row = wn * 32 + nb * 16 + l15;
        int cs = (ks * 4 + lg) ^ (row & 7);
        bfr[nb] = *(const bf16x8*)&sB[buf][row * 64 + cs * 8];
      }
#pragma unroll
      for (int mb = 0; mb < 2; ++mb)
#pragma unroll
        for (int nb = 0; nb < 2; ++nb)
          acc[mb][nb] = __builtin_amdgcn_mfma_f32_16x16x32_bf16(af[mb], bfr[nb], acc[mb][nb], 0, 0, 0);
    }
  };

  // prologue: stage tile 0
  loadA(0);
  stageB(0, 0);
  writeA(0);
  __syncthreads();

  const int NT = 28;  // 1792 / 64
  int cur = 0;
  for (int t = 0; t < NT; ++t) {
    if (t + 1 < NT) {            // issue next tile's loads BEFORE compute
      stageB((t + 1) * 64, cur ^ 1);
      loadA((t + 1) * 64);
    }
    compute(cur);
    if (t + 1 < NT) writeA(cur ^ 1);
    __syncthreads();
    cur ^= 1;
  }

  // epilogue: fp32 direct store, bias = b1 + b2
  const int colb = row0B + wn * 32;
#pragma unroll
  for (int nb = 0; nb < 2; ++nb) {
    int col = colb + nb * 16 + l15;
    float bv = b1[col] + b2[col];
#pragma unroll
    for (int mb = 0; mb < 2; ++mb) {
      size_t rowb = row0A + wm * 32 + mb * 16 + lg * 4;
#pragma unroll
      for (int r = 0; r < 4; ++r)
        out[(rowb + r) * 512 + col] = acc[mb][nb][r] + bv;
    }
  }
}

// ---------- gated h-GEMMs (gamma!=0 path): z=0 -> h1, z=1 -> h2 ----------
__global__ __launch_bounds__(256) void gemm_h12(
    const float* __restrict__ x1, const float* __restrict__ x2,
    const unsigned short* __restrict__ WT1, const unsigned short* __restrict__ WT2,
    const float* __restrict__ b1, const float* __restrict__ b2,
    unsigned short* __restrict__ h1b, unsigned short* __restrict__ h2b,
    const float* __restrict__ gate)
{
  if (gate[0] == 0.0f) return;
  const int z = blockIdx.z;
  const float* A = z ? x2 : x1;
  const unsigned short* Bt = z ? WT2 : WT1;
  const float* bias = z ? b2 : b1;
  unsigned short* C = z ? h2b : h1b;
  const int K = z ? 1024 : 768;
  const int ldc = 512;

  __shared__ __align__(16) unsigned short sA[128 * 32];
  __shared__ __align__(16) unsigned short sB[128 * 32];
  const int tid = threadIdx.x;
  const int lane = tid & 63;
  const int w = tid >> 6;
  const int wm = w & 1, wn = w >> 1;
  const int l15 = lane & 15, lg = lane >> 4;
  const size_t row0A = (size_t)blockIdx.x * 128;
  const size_t row0B = (size_t)blockIdx.y * 128;
  f32x4 acc[4][4] = {};

  for (int kb = 0; kb < K; kb += 32) {
#pragma unroll
    for (int j = 0; j < 2; ++j) {
      int cc = (w * 2 + j) * 64 + lane;
      int r = cc >> 2, k8 = cc & 3;
      async_load16(&sB[(size_t)((w * 2 + j) * 64) * 8], Bt + (row0B + r) * K + kb + k8 * 8);
    }
    {
      // coalesced A staging: 128x32 f32 tile = 1024 f32x4 chunks, 4/thread
#pragma unroll
      for (int i = 0; i < 4; ++i) {
        int cc = i * 256 + tid;
        int row = cc >> 3, c4 = cc & 7;     // 8 chunks per 32-float row
        f32x4 v = *(const f32x4*)(A + (row0A + row) * K + kb + c4 * 4);
        u16x4 hv;
#pragma unroll
        for (int j = 0; j < 4; ++j) hv[j] = f2bf(v[j]);
        *(u16x4*)&sA[row * 32 + c4 * 4] = hv;
      }
    }
    __syncthreads();
    bf16x8 af[4], bfr[4];
#pragma unroll
    for (int mb = 0; mb < 4; ++mb)
      af[mb] = *(const bf16x8*)&sA[(wm * 64 + mb * 16 + l15) * 32 + lg * 8];
#pragma unroll
    for (int nb = 0; nb < 4; ++nb)
      bfr[nb] = *(const bf16x8*)&sB[(wn * 64 + nb * 16 + l15) * 32 + lg * 8];
#pragma unroll
    for (int mb = 0; mb < 4; ++mb)
#pragma unroll
      for (int nb = 0; nb < 4; ++nb)
        acc[mb][nb] = __builtin_amdgcn_mfma_f32_16x16x32_bf16(af[mb], bfr[nb], acc[mb][nb], 0, 0, 0);
    __syncthreads();
  }

  const int colb = (int)row0B + wn * 64;
#pragma unroll
  for (int nb = 0; nb < 4; ++nb) {
    int col = colb + nb * 16 + l15;
    float bv = bias[col];
#pragma unroll
    for (int mb = 0; mb < 4; ++mb) {
      size_t rowb = row0A + wm * 64 + mb * 16 + lg * 4;
#pragma unroll
      for (int r = 0; r < 4; ++r)
        C[(rowb + r) * ldc + col] = f2bf(acc[mb][nb][r] + bv);
    }
  }
}

// ---------- QKV projections: 3 GEMMs in one launch via blockIdx.z ----------
__global__ __launch_bounds__(256) void gemm_qkv(
    const unsigned short* __restrict__ Aq,
    const unsigned short* __restrict__ Akv,
    const unsigned short* __restrict__ Wq_, const unsigned short* __restrict__ Wk_,
    const unsigned short* __restrict__ Wv_,
    const float* __restrict__ bq_, const float* __restrict__ bk_,
    const float* __restrict__ bv_,
    unsigned short* __restrict__ P,
    const float* __restrict__ gate)
{
  if (gate[0] == 0.0f) return;
  const int z = blockIdx.z;
  const unsigned short* A  = (z == 0) ? Aq : Akv;
  const unsigned short* Bt = (z == 0) ? Wq_ : (z == 1 ? Wk_ : Wv_);
  const float* bias        = (z == 0) ? bq_ : (z == 1 ? bk_ : bv_);
  unsigned short* C = P + z * 512;
  const int K = 512, ldc = 1536;

  __shared__ __align__(16) unsigned short sA[128 * 32];
  __shared__ __align__(16) unsigned short sB[128 * 32];
  const int tid = threadIdx.x;
  const int lane = tid & 63;
  const int w = tid >> 6;
  const int wm = w & 1, wn = w >> 1;
  const int l15 = lane & 15, lg = lane >> 4;
  const size_t row0A = (size_t)blockIdx.x * 128;
  const size_t row0B = (size_t)blockIdx.y * 128;
  f32x4 acc[4][4] = {};

  for (int kb = 0; kb < K; kb += 32) {
#pragma unroll
    for (int j = 0; j < 2; ++j) {
      int cc = (w * 2 + j) * 64 + lane;
      int r = cc >> 2, k8 = cc & 3;
      async_load16(&sA[(size_t)((w * 2 + j) * 64) * 8], A + (row0A + r) * K + kb + k8 * 8);
      async_load16(&sB[(size_t)((w * 2 + j) * 64) * 8], Bt + (row0B + r) * K + kb + k8 * 8);
    }
    __syncthreads();
    bf16x8 af[4], bfr[4];
#pragma unroll
    for (int mb = 0; mb < 4; ++mb)
      af[mb] = *(const bf16x8*)&sA[(wm * 64 + mb * 16 + l15) * 32 + lg * 8];
#pragma unroll
    for (int nb = 0; nb < 4; ++nb)
      bfr[nb] = *(const bf16x8*)&sB[(wn * 64 + nb * 16 + l15) * 32 + lg * 8];
#pragma unroll
    for (int mb = 0; mb < 4; ++mb)
#pragma unroll
      for (int nb = 0; nb < 4; ++nb)
        acc[mb][nb] = __builtin_amdgcn_mfma_f32_16x16x32_bf16(af[mb], bfr[nb], acc[mb][nb], 0, 0, 0);
    __syncthreads();
  }

  const int colb = (int)row0B + wn * 64;
#pragma unroll
  for (int nb = 0; nb < 4; ++nb) {
    int col = colb + nb * 16 + l15;
    float bv = bias[col];
#pragma unroll
    for (int mb = 0; mb < 4; ++mb) {
      size_t rowb = row0A + wm * 64 + mb * 16 + lg * 4;
#pragma unroll
      for (int r = 0; r < 4; ++r)
        C[(rowb + r) * ldc + col] = f2bf(acc[mb][nb][r] + bv);
    }
  }
}

// ---------- flash attention (gamma!=0 path; gamma==0 -> no-op) ----------
#define LDQ 1536
__global__ __launch_bounds__(256) void flash_attn(
    const unsigned short* __restrict__ P,
    const unsigned short* __restrict__ f1,
    const unsigned short* __restrict__ h1b,
    const unsigned short* __restrict__ h2b,
    const float* __restrict__ gamma,
    unsigned short* __restrict__ f1out,
    float* __restrict__ out32,
    int dir)
{
  const float g0 = gamma[0];
  if (g0 == 0.0f) return;  // fused_h12_out already wrote the final output

  __shared__ __align__(16) unsigned short KVs[18432];
  __shared__ __align__(16) float Sred[4608];
  __shared__ __align__(16) unsigned short Pt[1152];
  __shared__ float mstate[32], lstate[32], alpha_s[32];

  const int tid = threadIdx.x;
  const int lane = tid & 63;
  const int w = tid >> 6;
  const int l15 = lane & 15, lg = lane >> 4;
  const int wbase = w * 128;
  const int qt = blockIdx.x;
  const int b = blockIdx.y;
  const size_t qrow0 = (size_t)b * 2048 + (size_t)qt * 32;
  const size_t krow0 = (size_t)b * 2048;

  if (tid < 32) { mstate[tid] = -1e30f; lstate[tid] = 0.f; }
  __syncthreads();

  bf16x8 qf[2][4];
#pragma unroll
  for (int mb = 0; mb < 2; ++mb)
#pragma unroll
    for (int ks = 0; ks < 4; ++ks)
      qf[mb][ks] = *(const bf16x8*)(P + (qrow0 + mb * 16 + l15) * LDQ + wbase + ks * 32 + lg * 8);

  f32x4 o[2][8] = {};

  const int srow = tid >> 3, ssub = tid & 7;
  const int kvp = tid & 15, dg = tid >> 4;

  for (int kt = 0; kt < 64; ++kt) {
    const size_t kvb = krow0 + (size_t)kt * 32;
#pragma unroll
    for (int i = 0; i < 8; ++i) {
      int cc = tid + i * 256;
      int r = cc >> 6, c8 = cc & 63;
      *(u16x8*)&KVs[r * 520 + c8 * 8] = *(const u16x8*)(P + (kvb + r) * LDQ + 512 + c8 * 8);
    }
    __syncthreads();

    f32x4 sacc[2][2] = {};
#pragma unroll
    for (int ks = 0; ks < 4; ++ks)
#pragma unroll
      for (int nb = 0; nb < 2; ++nb) {
        bf16x8 kf = *(const bf16x8*)&KVs[(nb * 16 + l15) * 520 + wbase + ks * 32 + lg * 8];
#pragma unroll
        for (int mb = 0; mb < 2; ++mb)
          sacc[mb][nb] = __builtin_amdgcn_mfma_f32_16x16x32_bf16(qf[mb][ks], kf, sacc[mb][nb], 0, 0, 0);
      }
#pragma unroll
    for (int mb = 0; mb < 2; ++mb)
#pragma unroll
      for (int nb = 0; nb < 2; ++nb)
#pragma unroll
        for (int r = 0; r < 4; ++r)
          Sred[w * 1152 + (mb * 16 + lg * 4 + r) * 36 + nb * 16 + l15] = sacc[mb][nb][r];
    __syncthreads();

    {
      f32x4 sv = {};
#pragma unroll
      for (int w2 = 0; w2 < 4; ++w2)
        sv += *(const f32x4*)&Sred[w2 * 1152 + srow * 36 + ssub * 4];
      const float scale = 0.044194173824159216f;
      sv *= scale;
      float mloc = fmaxf(fmaxf(sv[0], sv[1]), fmaxf(sv[2], sv[3]));
      mloc = fmaxf(mloc, __shfl_xor(mloc, 1));
      mloc = fmaxf(mloc, __shfl_xor(mloc, 2));
      mloc = fmaxf(mloc, __shfl_xor(mloc, 4));
      float mold = mstate[srow];
      float mnew = fmaxf(mold, mloc);
      const float LOG2E = 1.4426950408889634f;
      float p0 = exp2f((sv[0] - mnew) * LOG2E);
      float p1 = exp2f((sv[1] - mnew) * LOG2E);
      float p2 = exp2f((sv[2] - mnew) * LOG2E);
      float p3 = exp2f((sv[3] - mnew) * LOG2E);
      float lloc = p0 + p1 + p2 + p3;
      lloc += __shfl_xor(lloc, 1);
      lloc += __shfl_xor(lloc, 2);
      lloc += __shfl_xor(lloc, 4);
      float alpha = exp2f((mold - mnew) * LOG2E);
      if (ssub == 0) {
        mstate[srow] = mnew;
        lstate[srow] = lstate[srow] * alpha + lloc;
        alpha_s[srow] = alpha;
      }
      u16x4 pw;
      pw[0] = f2bf(p0); pw[1] = f2bf(p1); pw[2] = f2bf(p2); pw[3] = f2bf(p3);
      *(u16x4*)&Pt[srow * 36 + ssub * 4] = pw;
    }
#pragma unroll
    for (int i = 0; i < 4; ++i) {
      int d0 = (dg + i * 16) * 8;
      u16x8 v0 = *(const u16x8*)(P + (kvb + kvp * 2) * LDQ + 1024 + d0);
      u16x8 v1 = *(const u16x8*)(P + (kvb + kvp * 2 + 1) * LDQ + 1024 + d0);
#pragma unroll
      for (int j = 0; j < 8; ++j) {
        u16x2 t2; t2[0] = v0[j]; t2[1] = v1[j];
        *(u16x2*)&KVs[(d0 + j) * 36 + kvp * 2] = t2;
      }
    }
    __syncthreads();

    float al[2][4];
#pragma unroll
    for (int mb = 0; mb < 2; ++mb)
#pragma unroll
      for (int r = 0; r < 4; ++r)
        al[mb][r] = alpha_s[mb * 16 + lg * 4 + r];
#pragma unroll
    for (int mb = 0; mb < 2; ++mb)
#pragma unroll
      for (int nb = 0; nb < 8; ++nb)
#pragma unroll
        for (int r = 0; r < 4; ++r)
          o[mb][nb][r] *= al[mb][r];

    bf16x8 pf[2];
#pragma unroll
    for (int mb = 0; mb < 2; ++mb) {
      u16x4 lo = *(const u16x4*)&Pt[(mb * 16 + l15) * 36 + lg * 8];
      u16x4 hi = *(const u16x4*)&Pt[(mb * 16 + l15) * 36 + lg * 8 + 4];
      pf[mb] = as_bf16x8(__builtin_shufflevector(lo, hi, 0, 1, 2, 3, 4, 5, 6, 7));
    }
#pragma unroll
    for (int nb = 0; nb < 8; ++nb) {
      int d = wbase + nb * 16 + l15;
      u16x4 lo = *(const u16x4*)&KVs[d * 36 + lg * 8];
      u16x4 hi = *(const u16x4*)&KVs[d * 36 + lg * 8 + 4];
      bf16x8 vf = as_bf16x8(__builtin_shufflevector(lo, hi, 0, 1, 2, 3, 4, 5, 6, 7));
#pragma unroll
      for (int mb = 0; mb < 2; ++mb)
        o[mb][nb] = __builtin_amdgcn_mfma_f32_16x16x32_bf16(pf[mb], vf, o[mb][nb], 0, 0, 0);
    }
    __syncthreads();
  }

  float li[2][4];
#pragma unroll
  for (int mb = 0; mb < 2; ++mb)
#pragma unroll
    for (int r = 0; r < 4; ++r)
      li[mb][r] = 1.0f / lstate[mb * 16 + lg * 4 + r];

  if (dir == 0) {
#pragma unroll
    for (int mb = 0; mb < 2; ++mb)
#pragma unroll
      for (int nb = 0; nb < 8; ++nb)
#pragma unroll
        for (int r = 0; r < 4; ++r)
          f1out[(qrow0 + mb * 16 + lg * 4 + r) * 512 + wbase + nb * 16 + l15] =
              f2bf(o[mb][nb][r] * li[mb][r]);
  } else {
    float g = g0;
#pragma unroll
    for (int mb = 0; mb < 2; ++mb)
#pragma unroll
      for (int nb = 0; nb < 8; ++nb)
#pragma unroll
        for (int r = 0; r < 4; ++r) {
          size_t idx = (qrow0 + mb * 16 + lg * 4 + r) * 512 + wbase + nb * 16 + l15;
          float f1v = bf2f(f1[idx]);
          float f2v = o[mb][nb][r] * li[mb][r];
          out32[idx] = g * (f1v + f2v) + bf2f(h1b[idx]) + bf2f(h2b[idx]);
        }
  }
}

// ---------- launch ----------
extern "C" void kernel_launch(void* const* d_in, const int* in_sizes, int n_in,
                              void* d_out, int out_size, void* d_ws, size_t ws_size,
                              hipStream_t stream)
{
  const float* x1    = (const float*)d_in[0];
  const float* x2    = (const float*)d_in[1];
  const float* Wp1   = (const float*)d_in[2];
  const float* bp1   = (const float*)d_in[3];
  const float* Wp2   = (const float*)d_in[4];
  const float* bp2   = (const float*)d_in[5];
  const float* Wq    = (const float*)d_in[6];
  const float* bq    = (const float*)d_in[7];
  const float* Wk    = (const float*)d_in[8];
  const float* bk    = (const float*)d_in[9];
  const float* Wv    = (const float*)d_in[10];
  const float* bv    = (const float*)d_in[11];
  const float* gamma = (const float*)d_in[12];
  float* out = (float*)d_out;
  char* ws = (char*)d_ws;

  unsigned short* WTp1 = (unsigned short*)(ws + 0);          // 512x768 bf16
  unsigned short* WTp2 = (unsigned short*)(ws + 786432);     // 512x1024 bf16
  unsigned short* WTq  = (unsigned short*)(ws + 1835008);    // 512x512 bf16
  unsigned short* WTk  = (unsigned short*)(ws + 2359296);
  unsigned short* WTv  = (unsigned short*)(ws + 2883584);
  unsigned short* h1b  = (unsigned short*)(ws + 3407872);    // 16384x512 bf16
  unsigned short* h2b  = (unsigned short*)(ws + 20185088);   // 16384x512 bf16
  unsigned short* f1b  = (unsigned short*)(ws + 36962304);   // 16384x512 bf16
  unsigned short* P1   = (unsigned short*)(ws + 53739520);   // 16384x1536 bf16

  // 1: all transposes, LDS-tiled (QKV segments gamma-gated inside)
  transpose_all_lds<<<416, 256, 0, stream>>>(Wp1, Wp2, Wq, Wk, Wv,
                                             WTp1, WTp2, WTq, WTk, WTv, gamma);

  // 2: gamma==0 fast path — the entire answer in one GEMM (64x64 tiles)
  fused_h12_out<<<2048, 256, 0, stream>>>(x1, x2, WTp1, WTp2, bp1, bp2, out, gamma);

  // 3: gamma!=0 path — h1/h2 bf16 (gated, merged z=2)
  gemm_h12<<<dim3(128, 4, 2), 256, 0, stream>>>(x1, x2, WTp1, WTp2, bp1, bp2, h1b, h2b, gamma);

  // 4-5: direction 0 QKV + attention (gated)
  gemm_qkv<<<dim3(128, 4, 3), 256, 0, stream>>>(h1b, h2b, WTq, WTk, WTv, bq, bk, bv, P1, gamma);
  flash_attn<<<dim3(64, 8), 256, 0, stream>>>(P1, f1b, h1b, h2b, gamma, f1b, out, 0);

  // 6-7: direction 1 QKV + attention/combine (gated)
  gemm_qkv<<<dim3(128, 4, 3), 256, 0, stream>>>(h2b, h1b, WTq, WTk, WTv, bq, bk, bv, P1, gamma);
  flash_attn<<<dim3(64, 8), 256, 0, stream>>>(P1, f1b, h1b, h2b, gamma, f1b, out, 1);
}